// Round 11
// baseline (407.805 us; speedup 1.0000x reference)
//
#include <hip/hip_runtime.h>
#include <hip/hip_bf16.h>

#define NEG_SLOPE 0.2f
#define NINF (-1e30f)

#define BKT_BITS 7
#define BKT 128            // dsts per bucket
#define PB 256             // partition blocks

typedef __attribute__((ext_vector_type(8))) short s8v;
typedef __attribute__((ext_vector_type(4))) float f4v;

__device__ __forceinline__ unsigned short f2bf(float f) {
    unsigned u = __float_as_uint(f);
    u = (u + 0x7fffu + ((u >> 16) & 1u)) >> 16;
    return (unsigned short)u;
}
__device__ __forceinline__ float bf2f(unsigned short h) {
    return __uint_as_float(((unsigned)h) << 16);
}

// ========== CSR build: atomic-free two-pass partition + per-bucket sort ==========

__global__ __launch_bounds__(256) void hist_pb_k(
    const int* __restrict__ edst, int E, int Etot, int NBK, int EPB,
    int* __restrict__ counts)
{
    __shared__ int lh[1024];
    for (int i = threadIdx.x; i < NBK; i += 256) lh[i] = 0;
    __syncthreads();
    const int e0 = blockIdx.x * EPB;
    const int e1 = min(e0 + EPB, Etot);
    for (int i = e0 + threadIdx.x; i < e1; i += 256) {
        int d = (i < E) ? edst[i] : (i - E);
        atomicAdd(&lh[d >> BKT_BITS], 1);
    }
    __syncthreads();
    for (int b = threadIdx.x; b < NBK; b += 256)
        counts[b * PB + blockIdx.x] = lh[b];
}

__global__ __launch_bounds__(256) void scan_partial_k(
    const int* __restrict__ a, int L, int* __restrict__ partials)
{
    __shared__ int red[256];
    const int t = threadIdx.x;
    const int base = blockIdx.x * 1024 + t * 4;
    int sum = 0;
    #pragma unroll
    for (int k = 0; k < 4; ++k) {
        int i = base + k;
        if (i < L) sum += a[i];
    }
    red[t] = sum;
    __syncthreads();
    #pragma unroll
    for (int o = 128; o; o >>= 1) {
        if (t < o) red[t] += red[t + o];
        __syncthreads();
    }
    if (t == 0) partials[blockIdx.x] = red[0];
}

__global__ __launch_bounds__(256) void scan_partials_k(
    int* __restrict__ partials, int nb)
{
    __shared__ int sh[256];
    const int t = threadIdx.x;
    int v = (t < nb) ? partials[t] : 0;
    sh[t] = v;
    __syncthreads();
    #pragma unroll
    for (int o = 1; o < 256; o <<= 1) {
        int u = (t >= o) ? sh[t - o] : 0;
        __syncthreads();
        sh[t] += u;
        __syncthreads();
    }
    if (t < nb) partials[t] = sh[t] - v;  // exclusive
}

__global__ __launch_bounds__(256) void scan_final_k(
    int* __restrict__ a, const int* __restrict__ partials, int L)
{
    __shared__ int sh[256];
    const int t = threadIdx.x;
    const int base = blockIdx.x * 1024 + t * 4;
    int v[4];
    int sum = 0;
    #pragma unroll
    for (int k = 0; k < 4; ++k) {
        int i = base + k;
        v[k] = (i < L) ? a[i] : 0;
        sum += v[k];
    }
    sh[t] = sum;
    __syncthreads();
    #pragma unroll
    for (int o = 1; o < 256; o <<= 1) {
        int u = (t >= o) ? sh[t - o] : 0;
        __syncthreads();
        sh[t] += u;
        __syncthreads();
    }
    int run = sh[t] - sum + partials[blockIdx.x];
    #pragma unroll
    for (int k = 0; k < 4; ++k) {
        int i = base + k;
        if (i < L) a[i] = run;
        run += v[k];
    }
}

__global__ __launch_bounds__(256) void scatter_pb_k(
    const int* __restrict__ esrc, const int* __restrict__ edst,
    int E, int Etot, int NBK, int EPB,
    const int* __restrict__ cbase, unsigned* __restrict__ tmp)
{
    __shared__ int cur[1024];
    for (int b = threadIdx.x; b < NBK; b += 256)
        cur[b] = cbase[b * PB + blockIdx.x];
    __syncthreads();
    const int e0 = blockIdx.x * EPB;
    const int e1 = min(e0 + EPB, Etot);
    for (int i = e0 + threadIdx.x; i < e1; i += 256) {
        int d = (i < E) ? edst[i] : (i - E);
        int s = (i < E) ? esrc[i] : (i - E);
        int pos = atomicAdd(&cur[d >> BKT_BITS], 1);
        tmp[pos] = ((unsigned)s << BKT_BITS) | (unsigned)(d & (BKT - 1));
    }
}

__global__ __launch_bounds__(256) void bucket_finalize_k(
    const unsigned* __restrict__ tmp, const int* __restrict__ cbase,
    int N, int NBK, int Etot,
    int* __restrict__ rowptr, int* __restrict__ csr)
{
    __shared__ int cnt[BKT];
    __shared__ int off[BKT];
    const int b = blockIdx.x;
    const int t = threadIdx.x;
    const int start = cbase[b * PB];
    const int end = (b + 1 < NBK) ? cbase[(b + 1) * PB] : Etot;
    const int n0 = b << BKT_BITS;
    const int nn = min(BKT, N - n0);

    if (t < BKT) cnt[t] = 0;
    __syncthreads();
    for (int i = start + t; i < end; i += 256)
        atomicAdd(&cnt[tmp[i] & (BKT - 1)], 1);
    __syncthreads();
    if (t < BKT) off[t] = cnt[t];
    __syncthreads();
    #pragma unroll
    for (int o = 1; o < BKT; o <<= 1) {
        int u = (t >= o && t < BKT) ? off[t - o] : 0;
        __syncthreads();
        if (t < BKT) off[t] += u;
        __syncthreads();
    }
    if (t < BKT) {
        int ex = off[t] - cnt[t];
        if (t < nn) rowptr[n0 + t] = start + ex;
        cnt[t] = ex;
    }
    if (b == 0 && t == 0) rowptr[N] = Etot;
    __syncthreads();
    for (int i = start + t; i < end; i += 256) {
        unsigned w = tmp[i];
        int dl = w & (BKT - 1);
        int pos = atomicAdd(&cnt[dl], 1);
        csr[start + pos] = (int)(w >> BKT_BITS);
    }
}

// ===== prep: transpose + split W into bf16 hi/lo =====
__global__ __launch_bounds__(256) void prep_w_k(
    const float* __restrict__ W1, const float* __restrict__ W2,
    short* __restrict__ Wt1h, short* __restrict__ Wt1l,
    short* __restrict__ Wt2h, short* __restrict__ Wt2l)
{
    int t = blockIdx.x * 256 + threadIdx.x;
    if (t < 256 * 64) {
        int k = t >> 6, c = t & 63;
        float v = W1[t];
        unsigned short h = f2bf(v);
        unsigned short l = f2bf(v - bf2f(h));
        Wt1h[c * 256 + k] = (short)h;
        Wt1l[c * 256 + k] = (short)l;
    } else if (t < 256 * 64 + 64 * 32) {
        int e = t - 256 * 64;
        int k = e >> 5, c = e & 31;
        float v = W2[e];
        unsigned short h = f2bf(v);
        unsigned short l = f2bf(v - bf2f(h));
        Wt2h[c * 64 + k] = (short)h;
        Wt2l[c * 64 + k] = (short)l;
    }
}

// ===== MFMA GEMM (split-bf16), one-shot global_load_lds staging =====
// Each wave stages its OWN 16 rows x K fp32 into LDS via fire-and-forget
// global_load_lds (no dest VGPRs), ONE vmcnt(0) drain, then the whole K-loop
// runs from LDS + MFMA. No __syncthreads anywhere (waves use disjoint LDS).
// Bank conflicts on the 16-rows-same-column ds_read are fixed by an XOR
// swizzle applied BOTH at the global source (low3 of chunk ^= row&7; LDS
// stays linear for gload) and at the ds_read slot (same involution).
template <int K, int M, bool RELU_BIAS>
__global__ __launch_bounds__(256) void gemm_mfma_k(
    const float* __restrict__ X,
    const short* __restrict__ Wth, const short* __restrict__ Wtl,
    const float* __restrict__ a_s, const float* __restrict__ a_d,
    const float* __restrict__ bias_in,
    unsigned short* __restrict__ Hb, float* __restrict__ AS, float* __restrict__ AD,
    int N)
{
    constexpr int NT = M / 16;       // col tiles
    constexpr int KS = K / 32;       // k steps
    constexpr int CPR = K / 4;       // 16B chunks per row
    constexpr int RPC = 64 / CPR;    // rows per gload call (K=256:1, K=64:4)
    constexpr int CALLS = 16 / RPC;  // gload calls per wave
    __shared__ float Xs[4][16][K];   // K=256: 64KB, K=64: 16KB

    const int wave = threadIdx.x >> 6;
    const int lane = threadIdx.x & 63;
    const int lc = lane & 15;
    const int hi = lane >> 4;
    const int k8 = hi * 8;
    const int rb = blockIdx.x * 64;
    const int rw = rb + wave * 16;   // wave's first row

    // ---- stage: 16 rows x K fp32, XOR-swizzled source, linear LDS dest ----
    #pragma unroll
    for (int i = 0; i < CALLS; ++i) {
        int ri = i * RPC + lane / CPR;                   // row within wave tile
        int pc = lane % CPR;                             // chunk slot within row
        int cg = (pc & ~7) | ((pc ^ ri) & 7);            // global chunk (swizzled)
        int srow = min(rw + ri, N - 1);                  // clamp (stores masked)
        const float* src = X + (long)srow * K + cg * 4;
        void* ldst = (void*)&Xs[wave][i * RPC][0];       // wave-uniform base
        __builtin_amdgcn_global_load_lds(
            (const __attribute__((address_space(1))) unsigned*)src,
            (__attribute__((address_space(3))) unsigned*)ldst, 16, 0, 0);
    }
    asm volatile("s_waitcnt vmcnt(0)" ::: "memory");
    __builtin_amdgcn_sched_barrier(0);

    f4v acc[NT];
    #pragma unroll
    for (int c = 0; c < NT; ++c) acc[c] = (f4v){0.f, 0.f, 0.f, 0.f};

    #pragma unroll
    for (int ks = 0; ks < KS; ++ks) {
        // lane reads row lc, chunks j0,j0+1 (swizzled slots p0, p0^1)
        const int j0 = ks * 8 + hi * 2;
        const int p0 = (j0 & ~7) | ((j0 ^ lc) & 7);
        float4 f0 = *(const float4*)&Xs[wave][lc][p0 * 4];
        float4 f1 = *(const float4*)&Xs[wave][lc][(p0 ^ 1) * 4];
        float v[8] = {f0.x, f0.y, f0.z, f0.w, f1.x, f1.y, f1.z, f1.w};
        if (RELU_BIAS) {
            #pragma unroll
            for (int j = 0; j < 8; ++j) {
                float w = v[j] + bias_in[ks * 32 + k8 + j];
                v[j] = w > 0.f ? w : 0.f;
            }
        }
        s8v ah, al;
        #pragma unroll
        for (int j = 0; j < 8; ++j) {
            unsigned short h = f2bf(v[j]);
            ah[j] = (short)h;
            al[j] = (short)f2bf(v[j] - bf2f(h));
        }
        #pragma unroll
        for (int c = 0; c < NT; ++c) {
            const long wo = (long)(c * 16 + lc) * K + ks * 32 + k8;
            s8v bh = *(const s8v*)(Wth + wo);
            s8v bl = *(const s8v*)(Wtl + wo);
            acc[c] = __builtin_amdgcn_mfma_f32_16x16x32_bf16(ah, bh, acc[c], 0, 0, 0);
            acc[c] = __builtin_amdgcn_mfma_f32_16x16x32_bf16(al, bh, acc[c], 0, 0, 0);
            acc[c] = __builtin_amdgcn_mfma_f32_16x16x32_bf16(ah, bl, acc[c], 0, 0, 0);
        }
    }

    // ---- epilogue: store bf16 H, fused alpha dots ----
    float ps[4] = {0.f, 0.f, 0.f, 0.f}, pd[4] = {0.f, 0.f, 0.f, 0.f};
    #pragma unroll
    for (int c = 0; c < NT; ++c) {
        float asv = a_s[c * 16 + lc];
        float adv = a_d[c * 16 + lc];
        #pragma unroll
        for (int j = 0; j < 4; ++j) {
            float hval = acc[c][j];
            int grow = rw + hi * 4 + j;
            if (grow < N) Hb[(long)grow * M + c * 16 + lc] = f2bf(hval);
            ps[j] = fmaf(hval, asv, ps[j]);
            pd[j] = fmaf(hval, adv, pd[j]);
        }
    }
    #pragma unroll
    for (int j = 0; j < 4; ++j) {
        #pragma unroll
        for (int o = 8; o >= 1; o >>= 1) {
            ps[j] += __shfl_xor(ps[j], o);
            pd[j] += __shfl_xor(pd[j], o);
        }
    }
    if (lc == 0) {
        #pragma unroll
        for (int j = 0; j < 4; ++j) {
            int grow = rw + hi * 4 + j;
            if (grow < N) { AS[grow] = ps[j]; AD[grow] = pd[j]; }
        }
    }
}

// ===== fused softmax + aggregation over CSR (layer 1, M=64) =====
__global__ __launch_bounds__(256) void agg_csr_k(
    const int* __restrict__ rowptr, const int* __restrict__ csr_src,
    const float* __restrict__ as_, const float* __restrict__ ad_,
    const unsigned short* __restrict__ H, float* __restrict__ OUT, int N)
{
    constexpr int M = 64, LP = 32, EH = 2;
    __shared__ float lw[4][64];
    __shared__ int   ls[4][64];
    const int wave = threadIdx.x >> 6;
    const int lane = threadIdx.x & 63;
    const int d = blockIdx.x * 4 + wave;
    if (d >= N) return;
    const int r0 = rowptr[d];
    const int deg = rowptr[d + 1] - r0;
    const float adv = ad_[d];

    const int f2 = (lane % LP) * 2;
    const int eh = lane / LP;

    float m = NINF, den = 0.0f, acc0 = 0.0f, acc1 = 0.0f;
    for (int base = 0; base < deg; base += 64) {
        int j = base + lane;
        int s = 0;
        float e = NINF;
        if (j < deg) {
            s = csr_src[r0 + j];
            e = as_[s] + adv;
            e = e > 0.0f ? e : NEG_SLOPE * e;
        }
        float cm = e;
        #pragma unroll
        for (int o = 32; o; o >>= 1) cm = fmaxf(cm, __shfl_xor(cm, o));
        if (cm > m) {
            float sc = __expf(m - cm);
            acc0 *= sc; acc1 *= sc; den *= sc; m = cm;
        }
        float w = __expf(e - m);
        float wsum = w;
        #pragma unroll
        for (int o = 32; o; o >>= 1) wsum += __shfl_xor(wsum, o);
        den += wsum;
        lw[wave][lane] = w;
        ls[wave][lane] = s;
        int cnt = min(64, deg - base);
        #pragma unroll 4
        for (int jj = 0; jj < cnt; jj += EH) {
            int je = jj + eh;
            float wj = (je < cnt) ? lw[wave][je] : 0.0f;
            int   sj = (je < cnt) ? ls[wave][je] : 0;
            unsigned hv = *(const unsigned*)&H[(long)sj * M + f2];
            acc0 = fmaf(wj, bf2f((unsigned short)(hv & 0xffffu)), acc0);
            acc1 = fmaf(wj, bf2f((unsigned short)(hv >> 16)), acc1);
        }
    }
    #pragma unroll
    for (int o = LP; o < 64; o <<= 1) {
        acc0 += __shfl_xor(acc0, o);
        acc1 += __shfl_xor(acc1, o);
    }
    if (lane < LP) {
        float inv = 1.0f / den;
        *(float2*)&OUT[(long)d * M + f2] = make_float2(acc0 * inv, acc1 * inv);
    }
}

// ===== layer-2 aggregation with FUSED final FC: out[d] = relu(agg+b2).Wfc+bfc =====
__global__ __launch_bounds__(256) void agg_fc_k(
    const int* __restrict__ rowptr, const int* __restrict__ csr_src,
    const float* __restrict__ as_, const float* __restrict__ ad_,
    const unsigned short* __restrict__ H,
    const float* __restrict__ b2, const float* __restrict__ Wfc,
    const float* __restrict__ bfc,
    float* __restrict__ out, int N)
{
    constexpr int M = 32, LP = 16, EH = 4;
    __shared__ float lw[4][64];
    __shared__ int   ls[4][64];
    const int wave = threadIdx.x >> 6;
    const int lane = threadIdx.x & 63;
    const int d = blockIdx.x * 4 + wave;
    if (d >= N) return;
    const int r0 = rowptr[d];
    const int deg = rowptr[d + 1] - r0;
    const float adv = ad_[d];

    const int f2 = (lane % LP) * 2;
    const int eh = lane / LP;

    float m = NINF, den = 0.0f, acc0 = 0.0f, acc1 = 0.0f;
    for (int base = 0; base < deg; base += 64) {
        int j = base + lane;
        int s = 0;
        float e = NINF;
        if (j < deg) {
            s = csr_src[r0 + j];
            e = as_[s] + adv;
            e = e > 0.0f ? e : NEG_SLOPE * e;
        }
        float cm = e;
        #pragma unroll
        for (int o = 32; o; o >>= 1) cm = fmaxf(cm, __shfl_xor(cm, o));
        if (cm > m) {
            float sc = __expf(m - cm);
            acc0 *= sc; acc1 *= sc; den *= sc; m = cm;
        }
        float w = __expf(e - m);
        float wsum = w;
        #pragma unroll
        for (int o = 32; o; o >>= 1) wsum += __shfl_xor(wsum, o);
        den += wsum;
        lw[wave][lane] = w;
        ls[wave][lane] = s;
        int cnt = min(64, deg - base);
        #pragma unroll 4
        for (int jj = 0; jj < cnt; jj += EH) {
            int je = jj + eh;
            float wj = (je < cnt) ? lw[wave][je] : 0.0f;
            int   sj = (je < cnt) ? ls[wave][je] : 0;
            unsigned hv = *(const unsigned*)&H[(long)sj * M + f2];
            acc0 = fmaf(wj, bf2f((unsigned short)(hv & 0xffffu)), acc0);
            acc1 = fmaf(wj, bf2f((unsigned short)(hv >> 16)), acc1);
        }
    }
    #pragma unroll
    for (int o = LP; o < 64; o <<= 1) {
        acc0 += __shfl_xor(acc0, o);
        acc1 += __shfl_xor(acc1, o);
    }
    // fused bias + relu + FC dot
    float inv = 1.0f / den;
    float h0 = acc0 * inv + b2[f2];
    float h1 = acc1 * inv + b2[f2 + 1];
    h0 = h0 > 0.f ? h0 : 0.f;
    h1 = h1 > 0.f ? h1 : 0.f;
    float p = h0 * Wfc[f2] + h1 * Wfc[f2 + 1];
    #pragma unroll
    for (int o = 8; o >= 1; o >>= 1) p += __shfl_xor(p, o);
    if (lane == 0) out[d] = p + bfc[0];
}

extern "C" void kernel_launch(void* const* d_in, const int* in_sizes, int n_in,
                              void* d_out, int out_size, void* d_ws, size_t ws_size,
                              hipStream_t stream) {
    const float* x      = (const float*)d_in[0];
    const int*   eidx   = (const int*)d_in[1];
    const float* W1     = (const float*)d_in[2];
    const float* a_src1 = (const float*)d_in[3];
    const float* a_dst1 = (const float*)d_in[4];
    const float* b1     = (const float*)d_in[5];
    const float* W2     = (const float*)d_in[6];
    const float* a_src2 = (const float*)d_in[7];
    const float* a_dst2 = (const float*)d_in[8];
    const float* b2     = (const float*)d_in[9];
    const float* Wfc    = (const float*)d_in[10];
    const float* bfc    = (const float*)d_in[11];
    float* out = (float*)d_out;

    const int N = in_sizes[0] / 256;       // 100000
    const int E = in_sizes[1] / 2;         // 1600000
    const int Etot = E + N;                // 1700000
    const int* esrc = eidx;
    const int* edst = eidx + E;
    const int NBK = (N + BKT - 1) >> BKT_BITS;   // 782
    const int EPB = (Etot + PB - 1) / PB;        // 6641
    const int L   = NBK * PB;                    // 200192

    // ---- workspace bump allocator (256B-aligned regions) ----
    char* cur = (char*)d_ws;
    auto alloc = [&](size_t bytes) -> void* {
        void* r = (void*)cur;
        cur += (bytes + 255) & ~(size_t)255;
        return r;
    };
    int* rowptr   = (int*)alloc((size_t)(N + 1) * 4);
    int* counts   = (int*)alloc((size_t)L * 4);
    int* partials = (int*)alloc(1024);
    unsigned* tmp = (unsigned*)alloc((size_t)Etot * 4);
    int* csr      = (int*)alloc((size_t)Etot * 4);
    float* as1    = (float*)alloc((size_t)N * 4);
    float* ad1    = (float*)alloc((size_t)N * 4);
    float* as2    = (float*)alloc((size_t)N * 4);
    float* ad2    = (float*)alloc((size_t)N * 4);
    short* Wt1h   = (short*)alloc(16384 * 2);
    short* Wt1l   = (short*)alloc(16384 * 2);
    short* Wt2h   = (short*)alloc(2048 * 2);
    short* Wt2l   = (short*)alloc(2048 * 2);
    unsigned short* h1b = (unsigned short*)alloc((size_t)N * 64 * 2);
    unsigned short* h2b = (unsigned short*)alloc((size_t)N * 32 * 2);
    float* h1out  = (float*)alloc((size_t)N * 64 * 4);

    // ---- weight prep + CSR build (atomic-free partition) ----
    prep_w_k<<<72, 256, 0, stream>>>(W1, W2, Wt1h, Wt1l, Wt2h, Wt2l);
    {
        int nb1 = (L + 1023) / 1024;   // 196
        hist_pb_k<<<PB, 256, 0, stream>>>(edst, E, Etot, NBK, EPB, counts);
        scan_partial_k<<<nb1, 256, 0, stream>>>(counts, L, partials);
        scan_partials_k<<<1, 256, 0, stream>>>(partials, nb1);
        scan_final_k<<<nb1, 256, 0, stream>>>(counts, partials, L);
        scatter_pb_k<<<PB, 256, 0, stream>>>(esrc, edst, E, Etot, NBK, EPB, counts, tmp);
        bucket_finalize_k<<<NBK, 256, 0, stream>>>(tmp, counts, N, NBK, Etot, rowptr, csr);
    }

    const int gemmBlocks = (N + 63) / 64;
    const int aggBlocks  = (N + 3) / 4;

    // ---- layer 1 ----
    gemm_mfma_k<256, 64, false><<<gemmBlocks, 256, 0, stream>>>(
        x, Wt1h, Wt1l, a_src1, a_dst1, nullptr, h1b, as1, ad1, N);
    agg_csr_k<<<aggBlocks, 256, 0, stream>>>(
        rowptr, csr, as1, ad1, h1b, h1out, N);

    // ---- layer 2 (bias1 + relu fused into fragment read) ----
    gemm_mfma_k<64, 32, true><<<gemmBlocks, 256, 0, stream>>>(
        h1out, Wt2h, Wt2l, a_src2, a_dst2, b1, h2b, as2, ad2, N);

    // ---- layer-2 aggregation with fused final FC ----
    agg_fc_k<<<aggBlocks, 256, 0, stream>>>(
        rowptr, csr, as2, ad2, h2b, b2, Wfc, bfc, out, N);
}

// Round 12
// 381.104 us; speedup vs baseline: 1.0701x; 1.0701x over previous
//
#include <hip/hip_runtime.h>
#include <hip/hip_bf16.h>

#define NEG_SLOPE 0.2f
#define NINF (-1e30f)

#define BKT_BITS 7
#define BKT 128            // dsts per bucket
#define PB 256             // partition blocks

typedef __attribute__((ext_vector_type(8))) short s8v;
typedef __attribute__((ext_vector_type(4))) float f4v;

__device__ __forceinline__ unsigned short f2bf(float f) {
    unsigned u = __float_as_uint(f);
    u = (u + 0x7fffu + ((u >> 16) & 1u)) >> 16;
    return (unsigned short)u;
}
__device__ __forceinline__ float bf2f(unsigned short h) {
    return __uint_as_float(((unsigned)h) << 16);
}

// ========== CSR build: atomic-free two-pass partition + per-bucket sort ==========

__global__ __launch_bounds__(256) void hist_pb_k(
    const int* __restrict__ edst, int E, int Etot, int NBK, int EPB,
    int* __restrict__ counts)
{
    __shared__ int lh[1024];
    for (int i = threadIdx.x; i < NBK; i += 256) lh[i] = 0;
    __syncthreads();
    const int e0 = blockIdx.x * EPB;
    const int e1 = min(e0 + EPB, Etot);
    for (int i = e0 + threadIdx.x; i < e1; i += 256) {
        int d = (i < E) ? edst[i] : (i - E);
        atomicAdd(&lh[d >> BKT_BITS], 1);
    }
    __syncthreads();
    for (int b = threadIdx.x; b < NBK; b += 256)
        counts[b * PB + blockIdx.x] = lh[b];
}

__global__ __launch_bounds__(256) void scan_partial_k(
    const int* __restrict__ a, int L, int* __restrict__ partials)
{
    __shared__ int red[256];
    const int t = threadIdx.x;
    const int base = blockIdx.x * 1024 + t * 4;
    int sum = 0;
    #pragma unroll
    for (int k = 0; k < 4; ++k) {
        int i = base + k;
        if (i < L) sum += a[i];
    }
    red[t] = sum;
    __syncthreads();
    #pragma unroll
    for (int o = 128; o; o >>= 1) {
        if (t < o) red[t] += red[t + o];
        __syncthreads();
    }
    if (t == 0) partials[blockIdx.x] = red[0];
}

__global__ __launch_bounds__(256) void scan_partials_k(
    int* __restrict__ partials, int nb)
{
    __shared__ int sh[256];
    const int t = threadIdx.x;
    int v = (t < nb) ? partials[t] : 0;
    sh[t] = v;
    __syncthreads();
    #pragma unroll
    for (int o = 1; o < 256; o <<= 1) {
        int u = (t >= o) ? sh[t - o] : 0;
        __syncthreads();
        sh[t] += u;
        __syncthreads();
    }
    if (t < nb) partials[t] = sh[t] - v;  // exclusive
}

__global__ __launch_bounds__(256) void scan_final_k(
    int* __restrict__ a, const int* __restrict__ partials, int L)
{
    __shared__ int sh[256];
    const int t = threadIdx.x;
    const int base = blockIdx.x * 1024 + t * 4;
    int v[4];
    int sum = 0;
    #pragma unroll
    for (int k = 0; k < 4; ++k) {
        int i = base + k;
        v[k] = (i < L) ? a[i] : 0;
        sum += v[k];
    }
    sh[t] = sum;
    __syncthreads();
    #pragma unroll
    for (int o = 1; o < 256; o <<= 1) {
        int u = (t >= o) ? sh[t - o] : 0;
        __syncthreads();
        sh[t] += u;
        __syncthreads();
    }
    int run = sh[t] - sum + partials[blockIdx.x];
    #pragma unroll
    for (int k = 0; k < 4; ++k) {
        int i = base + k;
        if (i < L) a[i] = run;
        run += v[k];
    }
}

__global__ __launch_bounds__(256) void scatter_pb_k(
    const int* __restrict__ esrc, const int* __restrict__ edst,
    int E, int Etot, int NBK, int EPB,
    const int* __restrict__ cbase, unsigned* __restrict__ tmp)
{
    __shared__ int cur[1024];
    for (int b = threadIdx.x; b < NBK; b += 256)
        cur[b] = cbase[b * PB + blockIdx.x];
    __syncthreads();
    const int e0 = blockIdx.x * EPB;
    const int e1 = min(e0 + EPB, Etot);
    for (int i = e0 + threadIdx.x; i < e1; i += 256) {
        int d = (i < E) ? edst[i] : (i - E);
        int s = (i < E) ? esrc[i] : (i - E);
        int pos = atomicAdd(&cur[d >> BKT_BITS], 1);
        tmp[pos] = ((unsigned)s << BKT_BITS) | (unsigned)(d & (BKT - 1));
    }
}

__global__ __launch_bounds__(256) void bucket_finalize_k(
    const unsigned* __restrict__ tmp, const int* __restrict__ cbase,
    int N, int NBK, int Etot,
    int* __restrict__ rowptr, int* __restrict__ csr)
{
    __shared__ int cnt[BKT];
    __shared__ int off[BKT];
    const int b = blockIdx.x;
    const int t = threadIdx.x;
    const int start = cbase[b * PB];
    const int end = (b + 1 < NBK) ? cbase[(b + 1) * PB] : Etot;
    const int n0 = b << BKT_BITS;
    const int nn = min(BKT, N - n0);

    if (t < BKT) cnt[t] = 0;
    __syncthreads();
    for (int i = start + t; i < end; i += 256)
        atomicAdd(&cnt[tmp[i] & (BKT - 1)], 1);
    __syncthreads();
    if (t < BKT) off[t] = cnt[t];
    __syncthreads();
    #pragma unroll
    for (int o = 1; o < BKT; o <<= 1) {
        int u = (t >= o && t < BKT) ? off[t - o] : 0;
        __syncthreads();
        if (t < BKT) off[t] += u;
        __syncthreads();
    }
    if (t < BKT) {
        int ex = off[t] - cnt[t];
        if (t < nn) rowptr[n0 + t] = start + ex;
        cnt[t] = ex;
    }
    if (b == 0 && t == 0) rowptr[N] = Etot;
    __syncthreads();
    for (int i = start + t; i < end; i += 256) {
        unsigned w = tmp[i];
        int dl = w & (BKT - 1);
        int pos = atomicAdd(&cnt[dl], 1);
        csr[start + pos] = (int)(w >> BKT_BITS);
    }
}

// ===== prep: transpose + split W into bf16 hi/lo =====
__global__ __launch_bounds__(256) void prep_w_k(
    const float* __restrict__ W1, const float* __restrict__ W2,
    short* __restrict__ Wt1h, short* __restrict__ Wt1l,
    short* __restrict__ Wt2h, short* __restrict__ Wt2l)
{
    int t = blockIdx.x * 256 + threadIdx.x;
    if (t < 256 * 64) {
        int k = t >> 6, c = t & 63;
        float v = W1[t];
        unsigned short h = f2bf(v);
        unsigned short l = f2bf(v - bf2f(h));
        Wt1h[c * 256 + k] = (short)h;
        Wt1l[c * 256 + k] = (short)l;
    } else if (t < 256 * 64 + 64 * 32) {
        int e = t - 256 * 64;
        int k = e >> 5, c = e & 31;
        float v = W2[e];
        unsigned short h = f2bf(v);
        unsigned short l = f2bf(v - bf2f(h));
        Wt2h[c * 64 + k] = (short)h;
        Wt2l[c * 64 + k] = (short)l;
    }
}

// ===== LAYER-1 MFMA GEMM: B-in-registers, A dbuf-staged in LDS =====
// K=256, M=64. Each wave owns ONE 16-col tile (cols wave*16..+15): its full
// B operand (hi+lo, all K) lives in 64 VGPRs, preloaded once. Inner loop is
// ds_read(A) + 3 MFMA only — no global loads after the prologue. Alpha dots
// are partial per wave (16 cols) and reduced across waves via LDS.
__global__ __launch_bounds__(256) void gemm1_mfma_k(
    const float* __restrict__ X,
    const short* __restrict__ Wth, const short* __restrict__ Wtl,
    const float* __restrict__ a_s, const float* __restrict__ a_d,
    unsigned short* __restrict__ Hb, float* __restrict__ AS, float* __restrict__ AD,
    int N)
{
    constexpr int K = 256, KS = 8;
    __shared__ short Xhi[2][64][40];
    __shared__ short Xlo[2][64][40];
    __shared__ float asb[4][64];
    __shared__ float adb[4][64];

    const int wave = threadIdx.x >> 6;
    const int lane = threadIdx.x & 63;
    const int lc = lane & 15;
    const int hig = lane >> 4;
    const int k8 = hig * 8;
    const int rb = blockIdx.x * 64;

    const int trow = threadIdx.x >> 2;        // 0..63
    const int tseg = (threadIdx.x & 3) * 8;   // 0,8,16,24
    const int gr = rb + trow;
    const bool rok = gr < N;
    const float* xrow = X + (long)gr * K + tseg;

    // ---- B prologue: this wave's 16 cols, full K, into registers ----
    s8v bh_r[KS], bl_r[KS];
    {
        const long wbase = (long)(wave * 16 + lc) * K + k8;
        #pragma unroll
        for (int ks = 0; ks < KS; ++ks) {
            bh_r[ks] = *(const s8v*)(Wth + wbase + ks * 32);
            bl_r[ks] = *(const s8v*)(Wtl + wbase + ks * 32);
        }
    }

    f4v acc[4];
    #pragma unroll
    for (int rt = 0; rt < 4; ++rt) acc[rt] = (f4v){0.f, 0.f, 0.f, 0.f};

    // prologue: load + stage tile 0
    {
        float v[8];
        if (rok) {
            float4 v0 = *(const float4*)(xrow);
            float4 v1 = *(const float4*)(xrow + 4);
            v[0] = v0.x; v[1] = v0.y; v[2] = v0.z; v[3] = v0.w;
            v[4] = v1.x; v[5] = v1.y; v[6] = v1.z; v[7] = v1.w;
        } else {
            #pragma unroll
            for (int j = 0; j < 8; ++j) v[j] = 0.f;
        }
        s8v hv, lv;
        #pragma unroll
        for (int j = 0; j < 8; ++j) {
            unsigned short h = f2bf(v[j]);
            hv[j] = (short)h;
            lv[j] = (short)f2bf(v[j] - bf2f(h));
        }
        *(s8v*)&Xhi[0][trow][tseg] = hv;
        *(s8v*)&Xlo[0][trow][tseg] = lv;
    }

    #pragma unroll
    for (int ks = 0; ks < KS; ++ks) {
        // issue next tile's global loads before the barrier
        float vn[8];
        if (ks + 1 < KS) {
            if (rok) {
                float4 v0 = *(const float4*)(xrow + (ks + 1) * 32);
                float4 v1 = *(const float4*)(xrow + (ks + 1) * 32 + 4);
                vn[0] = v0.x; vn[1] = v0.y; vn[2] = v0.z; vn[3] = v0.w;
                vn[4] = v1.x; vn[5] = v1.y; vn[6] = v1.z; vn[7] = v1.w;
            } else {
                #pragma unroll
                for (int j = 0; j < 8; ++j) vn[j] = 0.f;
            }
        }
        __syncthreads();

        // MFMA phase: all 4 row-tiles, this wave's col tile, B from registers
        #pragma unroll
        for (int rt = 0; rt < 4; ++rt) {
            s8v ah = *(const s8v*)&Xhi[ks & 1][rt * 16 + lc][k8];
            s8v al = *(const s8v*)&Xlo[ks & 1][rt * 16 + lc][k8];
            acc[rt] = __builtin_amdgcn_mfma_f32_16x16x32_bf16(ah, bh_r[ks], acc[rt], 0, 0, 0);
            acc[rt] = __builtin_amdgcn_mfma_f32_16x16x32_bf16(al, bh_r[ks], acc[rt], 0, 0, 0);
            acc[rt] = __builtin_amdgcn_mfma_f32_16x16x32_bf16(ah, bl_r[ks], acc[rt], 0, 0, 0);
        }

        // stage next tile into the other buffer
        if (ks + 1 < KS) {
            s8v hv, lv;
            #pragma unroll
            for (int j = 0; j < 8; ++j) {
                unsigned short h = f2bf(vn[j]);
                hv[j] = (short)h;
                lv[j] = (short)f2bf(vn[j] - bf2f(h));
            }
            *(s8v*)&Xhi[(ks + 1) & 1][trow][tseg] = hv;
            *(s8v*)&Xlo[(ks + 1) & 1][trow][tseg] = lv;
        }
    }

    // ---- epilogue: store bf16 H (this wave's 16 cols, all 64 rows) ----
    const int col = wave * 16 + lc;
    const float asv = a_s[col];
    const float adv = a_d[col];
    #pragma unroll
    for (int rt = 0; rt < 4; ++rt) {
        #pragma unroll
        for (int j = 0; j < 4; ++j) {
            float hval = acc[rt][j];
            int grow = rb + rt * 16 + hig * 4 + j;
            if (grow < N) Hb[(long)grow * 64 + col] = f2bf(hval);
            // partial alpha dots over this wave's 16 cols
            float psv = hval * asv;
            float pdv = hval * adv;
            #pragma unroll
            for (int o = 8; o >= 1; o >>= 1) {
                psv += __shfl_xor(psv, o);
                pdv += __shfl_xor(pdv, o);
            }
            if (lc == 0) {
                asb[wave][rt * 16 + hig * 4 + j] = psv;
                adb[wave][rt * 16 + hig * 4 + j] = pdv;
            }
        }
    }
    __syncthreads();
    if (threadIdx.x < 64) {
        int r = threadIdx.x;
        if (rb + r < N) {
            AS[rb + r] = asb[0][r] + asb[1][r] + asb[2][r] + asb[3][r];
            AD[rb + r] = adb[0][r] + adb[1][r] + adb[2][r] + adb[3][r];
        }
    }
}

// ===== MFMA GEMM (split-bf16), double-buffered LDS staging (layer 2) =====
template <int K, int M, bool RELU_BIAS>
__global__ __launch_bounds__(256) void gemm_mfma_k(
    const float* __restrict__ X,
    const short* __restrict__ Wth, const short* __restrict__ Wtl,
    const float* __restrict__ a_s, const float* __restrict__ a_d,
    const float* __restrict__ bias_in,
    unsigned short* __restrict__ Hb, float* __restrict__ AS, float* __restrict__ AD,
    int N)
{
    constexpr int NT = M / 16;
    constexpr int KS = K / 32;
    __shared__ short Xhi[2][64][40];
    __shared__ short Xlo[2][64][40];

    const int wave = threadIdx.x >> 6;
    const int lane = threadIdx.x & 63;
    const int lc = lane & 15;
    const int k8 = (lane >> 4) * 8;
    const int rb = blockIdx.x * 64;

    const int trow = threadIdx.x >> 2;
    const int tseg = (threadIdx.x & 3) * 8;
    const int gr = rb + trow;
    const bool rok = gr < N;
    const float* xrow = X + (long)gr * K + tseg;

    f4v acc[NT];
    #pragma unroll
    for (int c = 0; c < NT; ++c) acc[c] = (f4v){0.f, 0.f, 0.f, 0.f};

    float v[8];
    {
        if (rok) {
            float4 v0 = *(const float4*)(xrow);
            float4 v1 = *(const float4*)(xrow + 4);
            v[0] = v0.x; v[1] = v0.y; v[2] = v0.z; v[3] = v0.w;
            v[4] = v1.x; v[5] = v1.y; v[6] = v1.z; v[7] = v1.w;
        } else {
            #pragma unroll
            for (int j = 0; j < 8; ++j) v[j] = 0.f;
        }
        if (RELU_BIAS) {
            #pragma unroll
            for (int j = 0; j < 8; ++j) {
                float w = v[j] + bias_in[tseg + j];
                v[j] = w > 0.f ? w : 0.f;
            }
        }
        s8v hv, lv;
        #pragma unroll
        for (int j = 0; j < 8; ++j) {
            unsigned short h = f2bf(v[j]);
            hv[j] = (short)h;
            lv[j] = (short)f2bf(v[j] - bf2f(h));
        }
        *(s8v*)&Xhi[0][trow][tseg] = hv;
        *(s8v*)&Xlo[0][trow][tseg] = lv;
    }

    for (int ks = 0; ks < KS; ++ks) {
        float vn[8];
        if (ks + 1 < KS) {
            if (rok) {
                float4 v0 = *(const float4*)(xrow + (ks + 1) * 32);
                float4 v1 = *(const float4*)(xrow + (ks + 1) * 32 + 4);
                vn[0] = v0.x; vn[1] = v0.y; vn[2] = v0.z; vn[3] = v0.w;
                vn[4] = v1.x; vn[5] = v1.y; vn[6] = v1.z; vn[7] = v1.w;
            } else {
                #pragma unroll
                for (int j = 0; j < 8; ++j) vn[j] = 0.f;
            }
        }
        __syncthreads();

        const int arow = wave * 16 + lc;
        s8v ah = *(const s8v*)&Xhi[ks & 1][arow][k8];
        s8v al = *(const s8v*)&Xlo[ks & 1][arow][k8];
        #pragma unroll
        for (int c = 0; c < NT; ++c) {
            const long wo = (long)(c * 16 + lc) * K + ks * 32 + k8;
            s8v bh = *(const s8v*)(Wth + wo);
            s8v bl = *(const s8v*)(Wtl + wo);
            acc[c] = __builtin_amdgcn_mfma_f32_16x16x32_bf16(ah, bh, acc[c], 0, 0, 0);
            acc[c] = __builtin_amdgcn_mfma_f32_16x16x32_bf16(al, bh, acc[c], 0, 0, 0);
            acc[c] = __builtin_amdgcn_mfma_f32_16x16x32_bf16(ah, bl, acc[c], 0, 0, 0);
        }

        if (ks + 1 < KS) {
            if (RELU_BIAS) {
                #pragma unroll
                for (int j = 0; j < 8; ++j) {
                    float w = vn[j] + bias_in[(ks + 1) * 32 + tseg + j];
                    vn[j] = w > 0.f ? w : 0.f;
                }
            }
            s8v hv, lv;
            #pragma unroll
            for (int j = 0; j < 8; ++j) {
                unsigned short h = f2bf(vn[j]);
                hv[j] = (short)h;
                lv[j] = (short)f2bf(vn[j] - bf2f(h));
            }
            *(s8v*)&Xhi[(ks + 1) & 1][trow][tseg] = hv;
            *(s8v*)&Xlo[(ks + 1) & 1][trow][tseg] = lv;
        }
    }

    float ps[4] = {0.f, 0.f, 0.f, 0.f}, pd[4] = {0.f, 0.f, 0.f, 0.f};
    #pragma unroll
    for (int c = 0; c < NT; ++c) {
        float asv = a_s[c * 16 + lc];
        float adv = a_d[c * 16 + lc];
        #pragma unroll
        for (int j = 0; j < 4; ++j) {
            float hval = acc[c][j];
            int grow = rb + wave * 16 + (lane >> 4) * 4 + j;
            if (grow < N) Hb[(long)grow * M + c * 16 + lc] = f2bf(hval);
            ps[j] = fmaf(hval, asv, ps[j]);
            pd[j] = fmaf(hval, adv, pd[j]);
        }
    }
    #pragma unroll
    for (int j = 0; j < 4; ++j) {
        #pragma unroll
        for (int o = 8; o >= 1; o >>= 1) {
            ps[j] += __shfl_xor(ps[j], o);
            pd[j] += __shfl_xor(pd[j], o);
        }
    }
    if (lc == 0) {
        #pragma unroll
        for (int j = 0; j < 4; ++j) {
            int grow = rb + wave * 16 + (lane >> 4) * 4 + j;
            if (grow < N) { AS[grow] = ps[j]; AD[grow] = pd[j]; }
        }
    }
}

// ===== fused softmax + aggregation over CSR (layer 1, M=64) =====
__global__ __launch_bounds__(256) void agg_csr_k(
    const int* __restrict__ rowptr, const int* __restrict__ csr_src,
    const float* __restrict__ as_, const float* __restrict__ ad_,
    const unsigned short* __restrict__ H, float* __restrict__ OUT, int N)
{
    constexpr int M = 64, LP = 32, EH = 2;
    __shared__ float lw[4][64];
    __shared__ int   ls[4][64];
    const int wave = threadIdx.x >> 6;
    const int lane = threadIdx.x & 63;
    const int d = blockIdx.x * 4 + wave;
    if (d >= N) return;
    const int r0 = rowptr[d];
    const int deg = rowptr[d + 1] - r0;
    const float adv = ad_[d];

    const int f2 = (lane % LP) * 2;
    const int eh = lane / LP;

    float m = NINF, den = 0.0f, acc0 = 0.0f, acc1 = 0.0f;
    for (int base = 0; base < deg; base += 64) {
        int j = base + lane;
        int s = 0;
        float e = NINF;
        if (j < deg) {
            s = csr_src[r0 + j];
            e = as_[s] + adv;
            e = e > 0.0f ? e : NEG_SLOPE * e;
        }
        float cm = e;
        #pragma unroll
        for (int o = 32; o; o >>= 1) cm = fmaxf(cm, __shfl_xor(cm, o));
        if (cm > m) {
            float sc = __expf(m - cm);
            acc0 *= sc; acc1 *= sc; den *= sc; m = cm;
        }
        float w = __expf(e - m);
        float wsum = w;
        #pragma unroll
        for (int o = 32; o; o >>= 1) wsum += __shfl_xor(wsum, o);
        den += wsum;
        lw[wave][lane] = w;
        ls[wave][lane] = s;
        int cnt = min(64, deg - base);
        #pragma unroll 4
        for (int jj = 0; jj < cnt; jj += EH) {
            int je = jj + eh;
            float wj = (je < cnt) ? lw[wave][je] : 0.0f;
            int   sj = (je < cnt) ? ls[wave][je] : 0;
            unsigned hv = *(const unsigned*)&H[(long)sj * M + f2];
            acc0 = fmaf(wj, bf2f((unsigned short)(hv & 0xffffu)), acc0);
            acc1 = fmaf(wj, bf2f((unsigned short)(hv >> 16)), acc1);
        }
    }
    #pragma unroll
    for (int o = LP; o < 64; o <<= 1) {
        acc0 += __shfl_xor(acc0, o);
        acc1 += __shfl_xor(acc1, o);
    }
    if (lane < LP) {
        float inv = 1.0f / den;
        *(float2*)&OUT[(long)d * M + f2] = make_float2(acc0 * inv, acc1 * inv);
    }
}

// ===== layer-2 aggregation with FUSED final FC: out[d] = relu(agg+b2).Wfc+bfc =====
__global__ __launch_bounds__(256) void agg_fc_k(
    const int* __restrict__ rowptr, const int* __restrict__ csr_src,
    const float* __restrict__ as_, const float* __restrict__ ad_,
    const unsigned short* __restrict__ H,
    const float* __restrict__ b2, const float* __restrict__ Wfc,
    const float* __restrict__ bfc,
    float* __restrict__ out, int N)
{
    constexpr int M = 32, LP = 16, EH = 4;
    __shared__ float lw[4][64];
    __shared__ int   ls[4][64];
    const int wave = threadIdx.x >> 6;
    const int lane = threadIdx.x & 63;
    const int d = blockIdx.x * 4 + wave;
    if (d >= N) return;
    const int r0 = rowptr[d];
    const int deg = rowptr[d + 1] - r0;
    const float adv = ad_[d];

    const int f2 = (lane % LP) * 2;
    const int eh = lane / LP;

    float m = NINF, den = 0.0f, acc0 = 0.0f, acc1 = 0.0f;
    for (int base = 0; base < deg; base += 64) {
        int j = base + lane;
        int s = 0;
        float e = NINF;
        if (j < deg) {
            s = csr_src[r0 + j];
            e = as_[s] + adv;
            e = e > 0.0f ? e : NEG_SLOPE * e;
        }
        float cm = e;
        #pragma unroll
        for (int o = 32; o; o >>= 1) cm = fmaxf(cm, __shfl_xor(cm, o));
        if (cm > m) {
            float sc = __expf(m - cm);
            acc0 *= sc; acc1 *= sc; den *= sc; m = cm;
        }
        float w = __expf(e - m);
        float wsum = w;
        #pragma unroll
        for (int o = 32; o; o >>= 1) wsum += __shfl_xor(wsum, o);
        den += wsum;
        lw[wave][lane] = w;
        ls[wave][lane] = s;
        int cnt = min(64, deg - base);
        #pragma unroll 4
        for (int jj = 0; jj < cnt; jj += EH) {
            int je = jj + eh;
            float wj = (je < cnt) ? lw[wave][je] : 0.0f;
            int   sj = (je < cnt) ? ls[wave][je] : 0;
            unsigned hv = *(const unsigned*)&H[(long)sj * M + f2];
            acc0 = fmaf(wj, bf2f((unsigned short)(hv & 0xffffu)), acc0);
            acc1 = fmaf(wj, bf2f((unsigned short)(hv >> 16)), acc1);
        }
    }
    #pragma unroll
    for (int o = LP; o < 64; o <<= 1) {
        acc0 += __shfl_xor(acc0, o);
        acc1 += __shfl_xor(acc1, o);
    }
    float inv = 1.0f / den;
    float h0 = acc0 * inv + b2[f2];
    float h1 = acc1 * inv + b2[f2 + 1];
    h0 = h0 > 0.f ? h0 : 0.f;
    h1 = h1 > 0.f ? h1 : 0.f;
    float p = h0 * Wfc[f2] + h1 * Wfc[f2 + 1];
    #pragma unroll
    for (int o = 8; o >= 1; o >>= 1) p += __shfl_xor(p, o);
    if (lane == 0) out[d] = p + bfc[0];
}

extern "C" void kernel_launch(void* const* d_in, const int* in_sizes, int n_in,
                              void* d_out, int out_size, void* d_ws, size_t ws_size,
                              hipStream_t stream) {
    const float* x      = (const float*)d_in[0];
    const int*   eidx   = (const int*)d_in[1];
    const float* W1     = (const float*)d_in[2];
    const float* a_src1 = (const float*)d_in[3];
    const float* a_dst1 = (const float*)d_in[4];
    const float* b1     = (const float*)d_in[5];
    const float* W2     = (const float*)d_in[6];
    const float* a_src2 = (const float*)d_in[7];
    const float* a_dst2 = (const float*)d_in[8];
    const float* b2     = (const float*)d_in[9];
    const float* Wfc    = (const float*)d_in[10];
    const float* bfc    = (const float*)d_in[11];
    float* out = (float*)d_out;

    const int N = in_sizes[0] / 256;       // 100000
    const int E = in_sizes[1] / 2;         // 1600000
    const int Etot = E + N;                // 1700000
    const int* esrc = eidx;
    const int* edst = eidx + E;
    const int NBK = (N + BKT - 1) >> BKT_BITS;   // 782
    const int EPB = (Etot + PB - 1) / PB;        // 6641
    const int L   = NBK * PB;                    // 200192

    // ---- workspace bump allocator (256B-aligned regions) ----
    char* cur = (char*)d_ws;
    auto alloc = [&](size_t bytes) -> void* {
        void* r = (void*)cur;
        cur += (bytes + 255) & ~(size_t)255;
        return r;
    };
    int* rowptr   = (int*)alloc((size_t)(N + 1) * 4);
    int* counts   = (int*)alloc((size_t)L * 4);
    int* partials = (int*)alloc(1024);
    unsigned* tmp = (unsigned*)alloc((size_t)Etot * 4);
    int* csr      = (int*)alloc((size_t)Etot * 4);
    float* as1    = (float*)alloc((size_t)N * 4);
    float* ad1    = (float*)alloc((size_t)N * 4);
    float* as2    = (float*)alloc((size_t)N * 4);
    float* ad2    = (float*)alloc((size_t)N * 4);
    short* Wt1h   = (short*)alloc(16384 * 2);
    short* Wt1l   = (short*)alloc(16384 * 2);
    short* Wt2h   = (short*)alloc(2048 * 2);
    short* Wt2l   = (short*)alloc(2048 * 2);
    unsigned short* h1b = (unsigned short*)alloc((size_t)N * 64 * 2);
    unsigned short* h2b = (unsigned short*)alloc((size_t)N * 32 * 2);
    float* h1out  = (float*)alloc((size_t)N * 64 * 4);

    // ---- weight prep + CSR build (atomic-free partition) ----
    prep_w_k<<<72, 256, 0, stream>>>(W1, W2, Wt1h, Wt1l, Wt2h, Wt2l);
    {
        int nb1 = (L + 1023) / 1024;   // 196
        hist_pb_k<<<PB, 256, 0, stream>>>(edst, E, Etot, NBK, EPB, counts);
        scan_partial_k<<<nb1, 256, 0, stream>>>(counts, L, partials);
        scan_partials_k<<<1, 256, 0, stream>>>(partials, nb1);
        scan_final_k<<<nb1, 256, 0, stream>>>(counts, partials, L);
        scatter_pb_k<<<PB, 256, 0, stream>>>(esrc, edst, E, Etot, NBK, EPB, counts, tmp);
        bucket_finalize_k<<<NBK, 256, 0, stream>>>(tmp, counts, N, NBK, Etot, rowptr, csr);
    }

    const int gemmBlocks = (N + 63) / 64;
    const int aggBlocks  = (N + 3) / 4;

    // ---- layer 1 (B-in-registers GEMM) ----
    gemm1_mfma_k<<<gemmBlocks, 256, 0, stream>>>(
        x, Wt1h, Wt1l, a_src1, a_dst1, h1b, as1, ad1, N);
    agg_csr_k<<<aggBlocks, 256, 0, stream>>>(
        rowptr, csr, as1, ad1, h1b, h1out, N);

    // ---- layer 2 (bias1 + relu fused into staging load) ----
    gemm_mfma_k<64, 32, true><<<gemmBlocks, 256, 0, stream>>>(
        h1out, Wt2h, Wt2l, a_src2, a_dst2, b1, h2b, as2, ad2, N);

    // ---- layer-2 aggregation with fused final FC ----
    agg_fc_k<<<aggBlocks, 256, 0, stream>>>(
        rowptr, csr, as2, ad2, h2b, b2, Wfc, bfc, out, N);
}